// Round 6
// baseline (459.825 us; speedup 1.0000x reference)
//
#include <hip/hip_runtime.h>
#include <float.h>
#include <math.h>

typedef __attribute__((ext_vector_type(8))) short bf16x8;
typedef __attribute__((ext_vector_type(4))) float f32x4;

// d_out float offsets (loss, quantized, perplexity, embedding, indices, encodings)
#define O_Q    1
#define O_PERP 8388609
#define O_EMB  8388610
#define O_IDX  9437186
#define O_ENC  9469954

// workspace float offsets: ETpk limb image at byte 0 (4 MB); Xpk at byte 8 MB (32 MB)
#define W_CB   1048576
#define W_CNT  1052672
#define W_BS   1056768
#define XPK_BYTE_OFF (8u << 20)

#define MARGIN 0.01f

__device__ __forceinline__ unsigned short bf16_rne(float x) {
    unsigned u = __float_as_uint(x);
    unsigned r = u + 0x7FFFu + ((u >> 16) & 1u);
    return (unsigned short)(r >> 16);
}

__device__ __forceinline__ void gld_lds16(const void* g, void* l) {
    __builtin_amdgcn_global_load_lds(
        (const __attribute__((address_space(1))) unsigned int*)g,
        (__attribute__((address_space(3))) unsigned int*)l, 16, 0, 0);
}

__device__ __forceinline__ unsigned long long u64min(unsigned long long a, unsigned long long b){ return a < b ? a : b; }
__device__ __forceinline__ unsigned long long u64max(unsigned long long a, unsigned long long b){ return a > b ? a : b; }

__device__ __forceinline__ unsigned long long packkey(float s, int k) {
    unsigned u = __float_as_uint(s);
    u = (u & 0x80000000u) ? ~u : (u | 0x80000000u);
    return ((unsigned long long)u << 32) | (unsigned)k;
}
__device__ __forceinline__ float unpackf(unsigned long long key) {
    unsigned u = (unsigned)(key >> 32);
    u = (u & 0x80000000u) ? (u & 0x7FFFFFFFu) : ~u;
    return __uint_as_float(u);
}

// ---- E -> limb image. chunk(kt,ks) 32KB = [limb2][codefrag16][64 units x 16B]
__global__ __launch_bounds__(256)
void k_prepE(const float* __restrict__ E, char* __restrict__ ETpk)
{
    int gid = blockIdx.x * 256 + threadIdx.x;   // 131072 = 4096 codes * 32 octets
    int code = gid >> 5, oct = gid & 31;
    const float* ep = E + (size_t)code * 256 + oct * 8;
    float4 a = *(const float4*)ep, c4 = *(const float4*)(ep + 4);
    float v[8] = {a.x, a.y, a.z, a.w, c4.x, c4.y, c4.z, c4.w};
    unsigned hw[8], lw[8];
#pragma unroll
    for (int i = 0; i < 8; ++i) {
        unsigned short h = bf16_rne(v[i]);
        float hf = __uint_as_float((unsigned)h << 16);
        hw[i] = h; lw[i] = bf16_rne(v[i] - hf);
    }
    uint4 vh = {hw[0]|(hw[1]<<16), hw[2]|(hw[3]<<16), hw[4]|(hw[5]<<16), hw[6]|(hw[7]<<16)};
    uint4 vl = {lw[0]|(lw[1]<<16), lw[2]|(lw[3]<<16), lw[4]|(lw[5]<<16), lw[6]|(lw[7]<<16)};
    int kt = code >> 8, cf = (code >> 4) & 15, row = code & 15;
    int dtv = oct >> 2, c = oct & 3;
    size_t chunk = (size_t)(kt * 8 + dtv) * 32768;
    *(uint4*)(ETpk + chunk + (size_t)((0*16 + cf) * 64 + (c*16 + row)) * 16) = vh;
    *(uint4*)(ETpk + chunk + (size_t)((1*16 + cf) * 64 + (c*16 + row)) * 16) = vl;
}

// ---- X -> limb image, per n-tile slice of 128KB: [ks8][limb2][tokfrag8][64 units x 16B]
__global__ __launch_bounds__(256)
void k_prepX(const float* __restrict__ X, char* __restrict__ Xpk)
{
    int lin = blockIdx.x * 256 + threadIdx.x;    // 131072 = 32768 tok * 4 octs
    int oct = lin >> 15;                          // 0..3 (k-octet within k32 slice)
    int tok = lin & 32767;
    int nt = tok >> 7, tokA = tok & 127;
    int bt = tok >> 10, l = tok & 1023;
    const float* xp = X + (size_t)bt * 262144 + l;
    char* dst0 = Xpk + (size_t)nt * 131072 + (size_t)(tokA >> 4) * 1024
               + (size_t)((oct << 4) | (tokA & 15)) * 16;
#pragma unroll 1
    for (int ks = 0; ks < 8; ++ks) {
        float v[8];
#pragma unroll
        for (int i = 0; i < 8; ++i)
            v[i] = xp[(size_t)(ks * 32 + oct * 8 + i) * 1024];
        unsigned hw[8], lw[8];
#pragma unroll
        for (int i = 0; i < 8; ++i) {
            unsigned short h = bf16_rne(v[i]);
            float hf = __uint_as_float((unsigned)h << 16);
            hw[i] = h; lw[i] = bf16_rne(v[i] - hf);
        }
        uint4 vh = {hw[0]|(hw[1]<<16), hw[2]|(hw[3]<<16), hw[4]|(hw[5]<<16), hw[6]|(hw[7]<<16)};
        uint4 vl = {lw[0]|(lw[1]<<16), lw[2]|(lw[3]<<16), lw[4]|(lw[5]<<16), lw[6]|(lw[7]<<16)};
        *(uint4*)(dst0 + ks * 16384)        = vh;
        *(uint4*)(dst0 + ks * 16384 + 8192) = vl;
    }
}

// ---- 0.5*||e_k||^2 (fp32)
__global__ __launch_bounds__(256)
void k_cbias(const float* __restrict__ E, float* __restrict__ cb)
{
    const int tid = threadIdx.x;
    const int k   = blockIdx.x * 16 + (tid >> 4);
    const int ch  = tid & 15;
    const float* p = E + (size_t)k * 256 + ch * 16;
    float s = 0.f;
#pragma unroll
    for (int i = 0; i < 4; ++i) {
        float4 v = *(const float4*)(p + i * 4);
        s += v.x*v.x + v.y*v.y + v.z*v.z + v.w*v.w;
    }
#pragma unroll
    for (int m = 1; m < 16; m <<= 1) s += __shfl_xor(s, m, 64);
    if (ch == 0) cb[k] = 0.5f * s;
}

// ---- main: 3-combo limb MFMA + top2 + rescore + fused outputs.
// grid 256, block 512 (8 waves 2Mx4N), tile 128 tok x 256 codes/kt, k32 steps.
// LDS: 3 slots x 48KB (A 16K + B 32K), staged 2 rds ahead, counted vmcnt.
// PRE=1: A from pre-limbed Xpk via global_load_lds. PRE=0: round-4 writeA path.
template<int PRE>
__global__ __launch_bounds__(512, 1)
void k_main(const float* __restrict__ X, const char* __restrict__ ETpk,
            const char* __restrict__ Xpk, const float* __restrict__ cbh,
            const float* __restrict__ E, float* __restrict__ out,
            int* __restrict__ counts, float* __restrict__ bscore)
{
    extern __shared__ char lds[];

    const int tid  = threadIdx.x;
    const int lane = tid & 63;
    const int wid  = tid >> 6;
    const int wm   = wid >> 2;      // 0..1 token half
    const int wn   = wid & 3;       // 0..3 code quarter
    const int n0   = blockIdx.x * 128;
    const int b    = n0 >> 10;
    const int l0   = n0 & 1023;
    const int tokA = tid & 127;     // fallback A-staging unit
    const int octA = tid >> 7;

    f32x4 acc[4][4];
#pragma unroll
    for (int mi = 0; mi < 4; ++mi)
#pragma unroll
        for (int nj = 0; nj < 4; ++nj) acc[mi][nj] = (f32x4){0.f,0.f,0.f,0.f};

    float s1[16], s2[16];
    unsigned ipack[16];
#pragma unroll
    for (int s = 0; s < 16; ++s) { s1[s] = FLT_MAX; s2[s] = FLT_MAX; ipack[s] = 0; }

    const size_t xbase = (size_t)b * 262144 + l0;
    const char* XpkBlk = Xpk + (size_t)blockIdx.x * 131072;
    float* encB = out + (size_t)O_ENC + (size_t)n0 * 4096;   // base ≡ 2 mod 4: float2 ops

    auto stageB = [&](int rnd, int slot) {
        const char* src = ETpk + (size_t)rnd * 32768;
        char* dst = lds + slot * 49152 + 16384;
#pragma unroll
        for (int i = 0; i < 4; ++i)
            gld_lds16(src + i*8192 + tid*16, dst + i*8192 + tid*16);
    };
    auto stageA = [&](int rnd, int slot) {
        const char* src = XpkBlk + (size_t)(rnd & 7) * 16384;
        char* dst = lds + slot * 49152;
#pragma unroll
        for (int i = 0; i < 2; ++i)
            gld_lds16(src + i*8192 + tid*16, dst + i*8192 + tid*16);
    };
    auto loadA = [&](int rnd, float* xa) {
        const float* src = X + xbase + (size_t)((rnd & 7) * 32 + octA * 8) * 1024 + tokA;
#pragma unroll
        for (int i = 0; i < 8; ++i) xa[i] = src[(size_t)i * 1024];
    };
    auto writeA = [&](int slot, const float* xa) {
        unsigned hw[8], lw[8];
#pragma unroll
        for (int i = 0; i < 8; ++i) {
            unsigned short h16 = bf16_rne(xa[i]);
            float hf = __uint_as_float((unsigned)h16 << 16);
            hw[i] = h16; lw[i] = bf16_rne(xa[i] - hf);
        }
        uint4 vh = {hw[0]|(hw[1]<<16), hw[2]|(hw[3]<<16), hw[4]|(hw[5]<<16), hw[6]|(hw[7]<<16)};
        uint4 vl = {lw[0]|(lw[1]<<16), lw[2]|(lw[3]<<16), lw[4]|(lw[5]<<16), lw[6]|(lw[7]<<16)};
        char* dstc = lds + slot * 49152 + (tokA >> 4) * 1024 + (octA * 16 + (tokA & 15)) * 16;
        *(uint4*)dstc = vh;
        *(uint4*)(dstc + 8192) = vl;
    };

    // prologue: slots 0,1 staged; full drain once
    if (PRE) {
        stageA(0, 0); stageB(0, 0);
        stageA(1, 1); stageB(1, 1);
    } else {
        float xa0[8];
        loadA(0, xa0);
        stageB(0, 0); stageB(1, 1);
        writeA(0, xa0);
    }
    __syncthreads();

#pragma unroll 1
    for (int rd = 0; rd < 128; ++rd) {
        const int slot = rd % 3;
        const char* A  = lds + slot * 49152;
        const char* Bp = A + 16384;
        const int r2  = (rd + 2 < 128) ? rd + 2 : 127;
        const int sl2 = (rd + 2) % 3;
        float xa[8];
        if (PRE) {
            stageA(r2, sl2);
            stageB(r2, sl2);
        } else {
            loadA(rd + 1 < 128 ? rd + 1 : 127, xa);
            stageB(r2, sl2);
        }
        {   // zero-fill one token row of the one-hot block (4 float2/thread)
            float2 z2 = make_float2(0.f, 0.f);
            float* zb = encB + (size_t)rd * 4096;
#pragma unroll
            for (int i = 0; i < 4; ++i)
                *(float2*)(zb + i * 1024 + tid * 2) = z2;
        }

        // one k32-step, 3 limb combos (hh, lh, hl — ll dropped, err << MARGIN)
        {
            bf16x8 ah[4], al[4], bt[4];
#pragma unroll
            for (int mi = 0; mi < 4; ++mi)
                ah[mi] = *(const bf16x8*)(A + (wm*4 + mi)*1024 + lane*16);
#pragma unroll
            for (int nj = 0; nj < 4; ++nj)
                bt[nj] = *(const bf16x8*)(Bp + (wn*4 + nj)*1024 + lane*16);
#pragma unroll
            for (int nj = 0; nj < 4; ++nj)
#pragma unroll
                for (int mi = 0; mi < 4; ++mi)
                    acc[mi][nj] = __builtin_amdgcn_mfma_f32_16x16x32_bf16(ah[mi], bt[nj], acc[mi][nj], 0, 0, 0);
#pragma unroll
            for (int mi = 0; mi < 4; ++mi)
                al[mi] = *(const bf16x8*)(A + 8192 + (wm*4 + mi)*1024 + lane*16);
#pragma unroll
            for (int nj = 0; nj < 4; ++nj)
#pragma unroll
                for (int mi = 0; mi < 4; ++mi)
                    acc[mi][nj] = __builtin_amdgcn_mfma_f32_16x16x32_bf16(al[mi], bt[nj], acc[mi][nj], 0, 0, 0);
#pragma unroll
            for (int nj = 0; nj < 4; ++nj)
                bt[nj] = *(const bf16x8*)(Bp + 16384 + (wn*4 + nj)*1024 + lane*16);
#pragma unroll
            for (int nj = 0; nj < 4; ++nj)
#pragma unroll
                for (int mi = 0; mi < 4; ++mi)
                    acc[mi][nj] = __builtin_amdgcn_mfma_f32_16x16x32_bf16(ah[mi], bt[nj], acc[mi][nj], 0, 0, 0);
        }

        if ((rd & 7) == 7) {
            const int kt = rd >> 3;
            const int cb0 = kt * 256 + wn * 64 + (lane & 15);
            float cbv[4];
#pragma unroll
            for (int nj = 0; nj < 4; ++nj) cbv[nj] = cbh[cb0 + nj * 16];
#pragma unroll
            for (int mi = 0; mi < 4; ++mi)
#pragma unroll
                for (int q = 0; q < 4; ++q) {
                    const int slot2 = mi * 4 + q;
#pragma unroll
                    for (int nj = 0; nj < 4; ++nj) {
                        float s = cbv[nj] - acc[mi][nj][q];
                        unsigned code = (unsigned)(cb0 + nj * 16);
                        if (s < s1[slot2]) {
                            s2[slot2] = s1[slot2];
                            ipack[slot2] = ((ipack[slot2] & 0xFFFFu) << 16) | code;
                            s1[slot2] = s;
                        } else if (s < s2[slot2]) {
                            s2[slot2] = s;
                            ipack[slot2] = (ipack[slot2] & 0xFFFFu) | (code << 16);
                        }
                        acc[mi][nj][q] = 0.f;
                    }
                }
        }

        if (!PRE) writeA((rd + 1) % 3, xa);
        if (PRE) {
            // newest 10 = stageA(2)+stageB(4)+stores(4); forces slot rd+1 ready,
            // leaves rd+2 stage + this rd's stores in flight across the barrier
            asm volatile("s_waitcnt vmcnt(10)" ::: "memory");
        } else {
            asm volatile("s_waitcnt vmcnt(8)" ::: "memory");
            asm volatile("s_waitcnt lgkmcnt(0)" ::: "memory");
        }
        __builtin_amdgcn_s_barrier();
    }

    __syncthreads();   // full drain: store-acks (zero -> one-hot ordering) + LDS reuse

    // pack + butterfly-merge top2 across the 16 code-lanes
    unsigned long long key1[16], key2[16];
#pragma unroll
    for (int s = 0; s < 16; ++s) {
        key1[s] = packkey(s1[s], (int)(ipack[s] & 0xFFFFu));
        key2[s] = packkey(s2[s], (int)(ipack[s] >> 16));
    }
#pragma unroll
    for (int m = 1; m < 16; m <<= 1) {
#pragma unroll
        for (int s = 0; s < 16; ++s) {
            unsigned long long o1 = __shfl_xor(key1[s], m, 64);
            unsigned long long o2 = __shfl_xor(key2[s], m, 64);
            unsigned long long lo = u64min(key1[s], o1);
            unsigned long long hi = u64min(u64max(key1[s], o1), u64min(key2[s], o2));
            key1[s] = lo; key2[s] = hi;
        }
    }

    unsigned long long* scr = (unsigned long long*)lds;       // 8 KB
    int* ids = (int*)(lds + 16384);                           // 128 ints
    float* wp = (float*)(lds + 16384 + 512);                  // 8 floats
    if ((lane & 15) == 0) {
#pragma unroll
        for (int mi = 0; mi < 4; ++mi)
#pragma unroll
            for (int q = 0; q < 4; ++q) {
                int slot = mi * 4 + q;
                int tl = wm * 64 + mi * 16 + ((lane >> 4) << 2) + q;
                scr[(tl * 4 + wn) * 2    ] = key1[slot];
                scr[(tl * 4 + wn) * 2 + 1] = key2[slot];
            }
    }
    __syncthreads();

    if (tid < 128) {
        unsigned long long a1 = scr[tid * 8], a2 = scr[tid * 8 + 1];
#pragma unroll
        for (int w = 1; w < 4; ++w) {
            unsigned long long b1 = scr[(tid * 4 + w) * 2];
            unsigned long long b2 = scr[(tid * 4 + w) * 2 + 1];
            unsigned long long lo = u64min(a1, b1);
            unsigned long long hi = u64min(u64max(a1, b1), u64min(a2, b2));
            a1 = lo; a2 = hi;
        }
        int k = (int)(a1 & 0xFFFFFFFFull);
        float g1 = unpackf(a1), g2 = unpackf(a2);
        if (g2 - g1 <= MARGIN) {
            int ka = k, kb = (int)(a2 & 0xFFFFFFFFull);
            float d1 = 0.f, d2 = 0.f;
            for (int d = 0; d < 256; d += 2) {
                float xv0 = X[xbase + (size_t)d * 1024 + tid];
                float xv1 = X[xbase + (size_t)(d + 1) * 1024 + tid];
                float e10 = E[(size_t)ka * 256 + d], e11 = E[(size_t)ka * 256 + d + 1];
                float e20 = E[(size_t)kb * 256 + d], e21 = E[(size_t)kb * 256 + d + 1];
                float f10 = xv0 - e10, f11 = xv1 - e11;
                float f20 = xv0 - e20, f21 = xv1 - e21;
                d1 += f10 * f10 + f11 * f11;
                d2 += f20 * f20 + f21 * f21;
            }
            if (d2 < d1 || (d2 == d1 && kb < ka)) k = kb;
        }
        ids[tid] = k;
        out[(size_t)O_IDX + n0 + tid] = (float)k;
        atomicAdd(&counts[k], 1);
        out[(size_t)O_ENC + (size_t)(n0 + tid) * 4096 + k] = 1.0f;
    }
    __syncthreads();

    // fused quantize (STE arithmetic) + exact fp32 loss partial
    float dl = 0.f;
#pragma unroll 4
    for (int r = 0; r < 64; ++r) {
        int lin = r * 512 + tid;
        int d = lin >> 7, t = lin & 127;
        float q  = E[(size_t)ids[t] * 256 + d];
        float xv = X[xbase + (size_t)d * 1024 + t];
        out[(size_t)O_Q + xbase + (size_t)d * 1024 + t] = xv + (q - xv);
        float df = q - xv;
        dl += df * df;
    }
#pragma unroll
    for (int m = 1; m < 64; m <<= 1) dl += __shfl_xor(dl, m, 64);
    if (lane == 0) wp[wid] = dl;
    __syncthreads();
    if (tid == 0) {
        float s = 0.f;
#pragma unroll
        for (int w = 0; w < 8; ++w) s += wp[w];
        bscore[blockIdx.x] = s;
    }
}

// ---- scalars: loss + perplexity
__global__ __launch_bounds__(256)
void k_final(const float* __restrict__ bscore, const int* __restrict__ counts,
             float* __restrict__ out)
{
    const int tid = threadIdx.x;
    float s = bscore[tid];
    float h = 0.f;
#pragma unroll
    for (int i = 0; i < 16; ++i) {
        float p = (float)counts[tid * 16 + i] * (1.0f / 32768.f);
        h += p * logf(p + 1e-10f);
    }
#pragma unroll
    for (int m = 1; m < 64; m <<= 1) {
        s += __shfl_xor(s, m, 64);
        h += __shfl_xor(h, m, 64);
    }
    __shared__ float rs[4], rh[4];
    if ((tid & 63) == 0) { rs[tid >> 6] = s; rh[tid >> 6] = h; }
    __syncthreads();
    if (tid == 0) {
        float S = rs[0] + rs[1] + rs[2] + rs[3];
        float H = rh[0] + rh[1] + rh[2] + rh[3];
        out[0]      = 0.25f * S / 8388608.f;
        out[O_PERP] = expf(-H);
    }
}

extern "C" void kernel_launch(void* const* d_in, const int* in_sizes, int n_in,
                              void* d_out, int out_size, void* d_ws, size_t ws_size,
                              hipStream_t stream)
{
    (void)in_sizes; (void)n_in; (void)out_size;
    const float* X = (const float*)d_in[0];
    const float* E = (const float*)d_in[1];
    float* out = (float*)d_out;
    float* ws  = (float*)d_ws;
    char*  ETpk   = (char*)ws;
    char*  Xpk    = (char*)ws + XPK_BYTE_OFF;
    float* cbh    = ws + W_CB;
    int*   counts = (int*)(ws + W_CNT);
    float* bsc    = ws + W_BS;

    const bool pre = ws_size >= (size_t)40 * 1024 * 1024;

    hipMemsetAsync(counts, 0, 4096 * sizeof(int), stream);
    k_prepE<<<512, 256, 0, stream>>>(E, ETpk);
    k_cbias<<<256, 256, 0, stream>>>(E, cbh);
    if (pre) {
        k_prepX<<<512, 256, 0, stream>>>(X, Xpk);
        hipFuncSetAttribute(reinterpret_cast<const void*>(&k_main<1>),
                            hipFuncAttributeMaxDynamicSharedMemorySize, 147456);
        k_main<1><<<256, 512, 147456, stream>>>(X, ETpk, Xpk, cbh, E, out, counts, bsc);
    } else {
        hipFuncSetAttribute(reinterpret_cast<const void*>(&k_main<0>),
                            hipFuncAttributeMaxDynamicSharedMemorySize, 147456);
        k_main<0><<<256, 512, 147456, stream>>>(X, ETpk, Xpk, cbh, E, out, counts, bsc);
    }
    k_final<<<1, 256, 0, stream>>>(bsc, counts, out);
    hipMemcpyAsync(out + O_EMB, E, (size_t)4096 * 256 * sizeof(float),
                   hipMemcpyDeviceToDevice, stream);
}

// Round 7
// 400.351 us; speedup vs baseline: 1.1486x; 1.1486x over previous
//
#include <hip/hip_runtime.h>
#include <float.h>
#include <math.h>

typedef __attribute__((ext_vector_type(8))) short bf16x8;
typedef __attribute__((ext_vector_type(4))) float f32x4;

// d_out float offsets (loss, quantized, perplexity, embedding, indices, encodings)
#define O_Q    1
#define O_PERP 8388609
#define O_EMB  8388610
#define O_IDX  9437186
#define O_ENC  9469954

// workspace float offsets: ETpk limb image at byte 0 (4 MB)
#define W_CB   1048576
#define W_CNT  1052672
#define W_BS   1056768

#define MARGIN 0.01f

__device__ __forceinline__ unsigned short bf16_rne(float x) {
    unsigned u = __float_as_uint(x);
    unsigned r = u + 0x7FFFu + ((u >> 16) & 1u);
    return (unsigned short)(r >> 16);
}

__device__ __forceinline__ void gld_lds16(const void* g, void* l) {
    __builtin_amdgcn_global_load_lds(
        (const __attribute__((address_space(1))) unsigned int*)g,
        (__attribute__((address_space(3))) unsigned int*)l, 16, 0, 0);
}

__device__ __forceinline__ unsigned long long u64min(unsigned long long a, unsigned long long b){ return a < b ? a : b; }
__device__ __forceinline__ unsigned long long u64max(unsigned long long a, unsigned long long b){ return a > b ? a : b; }

__device__ __forceinline__ unsigned long long packkey(float s, int k) {
    unsigned u = __float_as_uint(s);
    u = (u & 0x80000000u) ? ~u : (u | 0x80000000u);
    return ((unsigned long long)u << 32) | (unsigned)k;
}
__device__ __forceinline__ float unpackf(unsigned long long key) {
    unsigned u = (unsigned)(key >> 32);
    u = (u & 0x80000000u) ? (u & 0x7FFFFFFFu) : ~u;
    return __uint_as_float(u);
}

// ---- E -> limb image. chunk(kt,ks) 32KB = [limb2][codefrag16][64 units x 16B]
__global__ __launch_bounds__(256)
void k_prepE(const float* __restrict__ E, char* __restrict__ ETpk)
{
    int gid = blockIdx.x * 256 + threadIdx.x;   // 131072 = 4096 codes * 32 octets
    int code = gid >> 5, oct = gid & 31;
    const float* ep = E + (size_t)code * 256 + oct * 8;
    float4 a = *(const float4*)ep, c4 = *(const float4*)(ep + 4);
    float v[8] = {a.x, a.y, a.z, a.w, c4.x, c4.y, c4.z, c4.w};
    unsigned hw[8], lw[8];
#pragma unroll
    for (int i = 0; i < 8; ++i) {
        unsigned short h = bf16_rne(v[i]);
        float hf = __uint_as_float((unsigned)h << 16);
        hw[i] = h; lw[i] = bf16_rne(v[i] - hf);
    }
    uint4 vh = {hw[0]|(hw[1]<<16), hw[2]|(hw[3]<<16), hw[4]|(hw[5]<<16), hw[6]|(hw[7]<<16)};
    uint4 vl = {lw[0]|(lw[1]<<16), lw[2]|(lw[3]<<16), lw[4]|(lw[5]<<16), lw[6]|(lw[7]<<16)};
    int kt = code >> 8, cf = (code >> 4) & 15, row = code & 15;
    int dtv = oct >> 2, c = oct & 3;
    size_t chunk = (size_t)(kt * 8 + dtv) * 32768;
    *(uint4*)(ETpk + chunk + (size_t)((0*16 + cf) * 64 + (c*16 + row)) * 16) = vh;
    *(uint4*)(ETpk + chunk + (size_t)((1*16 + cf) * 64 + (c*16 + row)) * 16) = vl;
}

// ---- 0.5*||e_k||^2 (fp32)
__global__ __launch_bounds__(256)
void k_cbias(const float* __restrict__ E, float* __restrict__ cb)
{
    const int tid = threadIdx.x;
    const int k   = blockIdx.x * 16 + (tid >> 4);
    const int ch  = tid & 15;
    const float* p = E + (size_t)k * 256 + ch * 16;
    float s = 0.f;
#pragma unroll
    for (int i = 0; i < 4; ++i) {
        float4 v = *(const float4*)(p + i * 4);
        s += v.x*v.x + v.y*v.y + v.z*v.z + v.w*v.w;
    }
#pragma unroll
    for (int m = 1; m < 16; m <<= 1) s += __shfl_xor(s, m, 64);
    if (ch == 0) cb[k] = 0.5f * s;
}

// ---- main: A-resident-in-LDS 3-combo limb MFMA + top2 + rescore + fused outputs.
// grid 512, block 512 (8 waves 2Mx4N), tile 64 tok x 256 codes/kt, k32 steps.
// LDS 160KB: A resident 64KB [ks8][limb2][frag4][1KB] (split ONCE in prologue),
// B triple-buffered 3x32KB staged 2 rds ahead via global_load_lds, vmcnt(6).
__global__ __launch_bounds__(512, 1)
void k_main(const float* __restrict__ X, const char* __restrict__ ETpk,
            const float* __restrict__ cbh, const float* __restrict__ E,
            float* __restrict__ out, int* __restrict__ counts,
            float* __restrict__ bscore)
{
    extern __shared__ char lds[];
    char* Alds = lds;                 // 64 KB
    char* Bsl  = lds + 65536;         // 3 x 32 KB

    const int tid  = threadIdx.x;
    const int lane = tid & 63;
    const int wid  = tid >> 6;
    const int wm   = wid >> 2;        // 0..1 token half (32 tok)
    const int wn   = wid & 3;         // 0..3 code quarter (64 codes)
    const int n0   = blockIdx.x * 64;
    const int b    = n0 >> 10;
    const int l0   = n0 & 1023;
    const size_t xbase = (size_t)b * 262144 + l0;
    float* encB = out + (size_t)O_ENC + (size_t)n0 * 4096;   // ≡ 2 mod 4: float2 ops

    f32x4 acc[2][4];
#pragma unroll
    for (int mi = 0; mi < 2; ++mi)
#pragma unroll
        for (int nj = 0; nj < 4; ++nj) acc[mi][nj] = (f32x4){0.f,0.f,0.f,0.f};

    float s1[8], s2[8];
    unsigned ipack[8];
#pragma unroll
    for (int s = 0; s < 8; ++s) { s1[s] = FLT_MAX; s2[s] = FLT_MAX; ipack[s] = 0; }

    auto stageB = [&](int rnd, int slot) {
        const char* src = ETpk + (size_t)rnd * 32768;
        char* dst = Bsl + slot * 32768;
#pragma unroll
        for (int i = 0; i < 4; ++i)
            gld_lds16(src + i*8192 + tid*16, dst + i*8192 + tid*16);
    };

    // ---- prologue: stage B0,B1; load+split+write the WHOLE A tile once
    stageB(0, 0);
    stageB(1, 1);
    {
        const int t = tid & 63;       // token
        const int g = tid >> 6;       // octet group 0..7
#pragma unroll
        for (int jj = 0; jj < 4; ++jj) {
            const int j  = g + jj * 8;        // d-octet 0..31
            const int ks = j >> 2, c = j & 3;
            const float* xp = X + xbase + (size_t)(j * 8) * 1024 + t;
            float v[8];
#pragma unroll
            for (int i = 0; i < 8; ++i) v[i] = xp[(size_t)i * 1024];
            unsigned hw[8], lw[8];
#pragma unroll
            for (int i = 0; i < 8; ++i) {
                unsigned short h = bf16_rne(v[i]);
                float hf = __uint_as_float((unsigned)h << 16);
                hw[i] = h; lw[i] = bf16_rne(v[i] - hf);
            }
            uint4 vh = {hw[0]|(hw[1]<<16), hw[2]|(hw[3]<<16), hw[4]|(hw[5]<<16), hw[6]|(hw[7]<<16)};
            uint4 vl = {lw[0]|(lw[1]<<16), lw[2]|(lw[3]<<16), lw[4]|(lw[5]<<16), lw[6]|(lw[7]<<16)};
            char* d0 = Alds + ks * 8192 + (t >> 4) * 1024 + (c * 16 + (t & 15)) * 16;
            *(uint4*)d0          = vh;
            *(uint4*)(d0 + 4096) = vl;
        }
    }
    __syncthreads();

    // ---- main loop: 128 k32-steps (16 kt x 8 ks)
#pragma unroll 1
    for (int rd = 0; rd < 128; ++rd) {
        const char* A  = Alds + (rd & 7) * 8192;
        const char* Bp = Bsl + (rd % 3) * 32768;
        const int r2  = (rd + 2 < 128) ? rd + 2 : 127;
        stageB(r2, (rd + 2) % 3);
        {   // zero-fill 8KB of this block's one-hot region (2 float2/thread)
            float2 z2 = make_float2(0.f, 0.f);
            float* zb = encB + (size_t)rd * 2048 + tid * 2;
            *(float2*)zb            = z2;
            *(float2*)(zb + 1024)   = z2;
        }

        // 3 limb combos (hh, lh, hl), 24 MFMA
        {
            bf16x8 ah[2], al[2];
#pragma unroll
            for (int mi = 0; mi < 2; ++mi) {
                ah[mi] = *(const bf16x8*)(A + (wm*2 + mi)*1024 + lane*16);
                al[mi] = *(const bf16x8*)(A + 4096 + (wm*2 + mi)*1024 + lane*16);
            }
#pragma unroll
            for (int nj = 0; nj < 4; ++nj) {
                bf16x8 bh = *(const bf16x8*)(Bp + (wn*4 + nj)*1024 + lane*16);
                bf16x8 bl = *(const bf16x8*)(Bp + 16384 + (wn*4 + nj)*1024 + lane*16);
#pragma unroll
                for (int mi = 0; mi < 2; ++mi) {
                    acc[mi][nj] = __builtin_amdgcn_mfma_f32_16x16x32_bf16(ah[mi], bh, acc[mi][nj], 0, 0, 0);
                    acc[mi][nj] = __builtin_amdgcn_mfma_f32_16x16x32_bf16(al[mi], bh, acc[mi][nj], 0, 0, 0);
                    acc[mi][nj] = __builtin_amdgcn_mfma_f32_16x16x32_bf16(ah[mi], bl, acc[mi][nj], 0, 0, 0);
                }
            }
        }

        if ((rd & 7) == 7) {
            const int kt = rd >> 3;
            const int cb0 = kt * 256 + wn * 64 + (lane & 15);
            float cbv[4];
#pragma unroll
            for (int nj = 0; nj < 4; ++nj) cbv[nj] = cbh[cb0 + nj * 16];
#pragma unroll
            for (int mi = 0; mi < 2; ++mi)
#pragma unroll
                for (int q = 0; q < 4; ++q) {
                    const int slot = mi * 4 + q;
#pragma unroll
                    for (int nj = 0; nj < 4; ++nj) {
                        float s = cbv[nj] - acc[mi][nj][q];
                        unsigned code = (unsigned)(cb0 + nj * 16);
                        if (s < s1[slot]) {
                            s2[slot] = s1[slot];
                            ipack[slot] = ((ipack[slot] & 0xFFFFu) << 16) | code;
                            s1[slot] = s;
                        } else if (s < s2[slot]) {
                            s2[slot] = s;
                            ipack[slot] = (ipack[slot] & 0xFFFFu) | (code << 16);
                        }
                        acc[mi][nj][q] = 0.f;
                    }
                }
        }

        // counted wait: rd's 6 newest vmem ops (4 stageB(r2) + 2 stores) stay
        // in flight; everything older (incl. stageB(rd+1)) is complete
        asm volatile("s_waitcnt vmcnt(6)" ::: "memory");
        __builtin_amdgcn_s_barrier();
    }

    __syncthreads();   // full drain (store acks for zero->one-hot ordering, LDS reuse)

    // pack + butterfly-merge top2 across the 16 code-lanes
    unsigned long long key1[8], key2[8];
#pragma unroll
    for (int s = 0; s < 8; ++s) {
        key1[s] = packkey(s1[s], (int)(ipack[s] & 0xFFFFu));
        key2[s] = packkey(s2[s], (int)(ipack[s] >> 16));
    }
#pragma unroll
    for (int m = 1; m < 16; m <<= 1) {
#pragma unroll
        for (int s = 0; s < 8; ++s) {
            unsigned long long o1 = __shfl_xor(key1[s], m, 64);
            unsigned long long o2 = __shfl_xor(key2[s], m, 64);
            unsigned long long lo = u64min(key1[s], o1);
            unsigned long long hi = u64min(u64max(key1[s], o1), u64min(key2[s], o2));
            key1[s] = lo; key2[s] = hi;
        }
    }

    unsigned long long* scr = (unsigned long long*)lds;     // 64*4*2 u64 = 4 KB
    int* ids  = (int*)(lds + 4096);                         // 64 ints
    float* wp = (float*)(lds + 4096 + 256);                 // 8 floats
    if ((lane & 15) == 0) {
#pragma unroll
        for (int mi = 0; mi < 2; ++mi)
#pragma unroll
            for (int q = 0; q < 4; ++q) {
                int slot = mi * 4 + q;
                int tl = wm * 32 + mi * 16 + ((lane >> 4) << 2) + q;
                scr[(tl * 4 + wn) * 2    ] = key1[slot];
                scr[(tl * 4 + wn) * 2 + 1] = key2[slot];
            }
    }
    __syncthreads();

    if (tid < 64) {
        unsigned long long a1 = scr[tid * 8], a2 = scr[tid * 8 + 1];
#pragma unroll
        for (int w = 1; w < 4; ++w) {
            unsigned long long b1 = scr[(tid * 4 + w) * 2];
            unsigned long long b2 = scr[(tid * 4 + w) * 2 + 1];
            unsigned long long lo = u64min(a1, b1);
            unsigned long long hi = u64min(u64max(a1, b1), u64min(a2, b2));
            a1 = lo; a2 = hi;
        }
        int k = (int)(a1 & 0xFFFFFFFFull);
        float g1 = unpackf(a1), g2 = unpackf(a2);
        if (g2 - g1 <= MARGIN) {
            int ka = k, kb = (int)(a2 & 0xFFFFFFFFull);
            float d1 = 0.f, d2 = 0.f;
            for (int d = 0; d < 256; d += 2) {
                float xv0 = X[xbase + (size_t)d * 1024 + tid];
                float xv1 = X[xbase + (size_t)(d + 1) * 1024 + tid];
                float e10 = E[(size_t)ka * 256 + d], e11 = E[(size_t)ka * 256 + d + 1];
                float e20 = E[(size_t)kb * 256 + d], e21 = E[(size_t)kb * 256 + d + 1];
                float f10 = xv0 - e10, f11 = xv1 - e11;
                float f20 = xv0 - e20, f21 = xv1 - e21;
                d1 += f10 * f10 + f11 * f11;
                d2 += f20 * f20 + f21 * f21;
            }
            if (d2 < d1 || (d2 == d1 && kb < ka)) k = kb;
        }
        ids[tid] = k;
        out[(size_t)O_IDX + n0 + tid] = (float)k;
        atomicAdd(&counts[k], 1);
        out[(size_t)O_ENC + (size_t)(n0 + tid) * 4096 + k] = 1.0f;
    }
    __syncthreads();

    // fused quantize (STE arithmetic) + exact fp32 loss partial
    float dl = 0.f;
#pragma unroll 4
    for (int r = 0; r < 32; ++r) {
        int lin = r * 512 + tid;
        int d = lin >> 6, t = lin & 63;
        float q  = E[(size_t)ids[t] * 256 + d];
        float xv = X[xbase + (size_t)d * 1024 + t];
        out[(size_t)O_Q + xbase + (size_t)d * 1024 + t] = xv + (q - xv);
        float df = q - xv;
        dl += df * df;
    }
#pragma unroll
    for (int m = 1; m < 64; m <<= 1) dl += __shfl_xor(dl, m, 64);
    if (lane == 0) wp[wid] = dl;
    __syncthreads();
    if (tid == 0) {
        float s = 0.f;
#pragma unroll
        for (int w = 0; w < 8; ++w) s += wp[w];
        bscore[blockIdx.x] = s;
    }
}

// ---- scalars: loss + perplexity (512 block partials)
__global__ __launch_bounds__(256)
void k_final(const float* __restrict__ bscore, const int* __restrict__ counts,
             float* __restrict__ out)
{
    const int tid = threadIdx.x;
    float s = bscore[tid] + bscore[tid + 256];
    float h = 0.f;
#pragma unroll
    for (int i = 0; i < 16; ++i) {
        float p = (float)counts[tid * 16 + i] * (1.0f / 32768.f);
        h += p * logf(p + 1e-10f);
    }
#pragma unroll
    for (int m = 1; m < 64; m <<= 1) {
        s += __shfl_xor(s, m, 64);
        h += __shfl_xor(h, m, 64);
    }
    __shared__ float rs[4], rh[4];
    if ((tid & 63) == 0) { rs[tid >> 6] = s; rh[tid >> 6] = h; }
    __syncthreads();
    if (tid == 0) {
        float S = rs[0] + rs[1] + rs[2] + rs[3];
        float H = rh[0] + rh[1] + rh[2] + rh[3];
        out[0]      = 0.25f * S / 8388608.f;
        out[O_PERP] = expf(-H);
    }
}

extern "C" void kernel_launch(void* const* d_in, const int* in_sizes, int n_in,
                              void* d_out, int out_size, void* d_ws, size_t ws_size,
                              hipStream_t stream)
{
    (void)in_sizes; (void)n_in; (void)out_size; (void)ws_size;
    const float* X = (const float*)d_in[0];
    const float* E = (const float*)d_in[1];
    float* out = (float*)d_out;
    float* ws  = (float*)d_ws;
    char*  ETpk   = (char*)ws;
    float* cbh    = ws + W_CB;
    int*   counts = (int*)(ws + W_CNT);
    float* bsc    = ws + W_BS;

    hipMemsetAsync(counts, 0, 4096 * sizeof(int), stream);
    k_prepE<<<512, 256, 0, stream>>>(E, ETpk);
    k_cbias<<<256, 256, 0, stream>>>(E, cbh);
    hipFuncSetAttribute(reinterpret_cast<const void*>(&k_main),
                        hipFuncAttributeMaxDynamicSharedMemorySize, 163840);
    k_main <<<512, 512, 163840, stream>>>(X, ETpk, cbh, E, out, counts, bsc);
    k_final<<<1, 256, 0, stream>>>(bsc, counts, out);
    hipMemcpyAsync(out + O_EMB, E, (size_t)4096 * 256 * sizeof(float),
                   hipMemcpyDeviceToDevice, stream);
}

// Round 9
// 378.667 us; speedup vs baseline: 1.2143x; 1.0573x over previous
//
#include <hip/hip_runtime.h>
#include <float.h>
#include <math.h>

typedef __attribute__((ext_vector_type(8))) short bf16x8;
typedef __attribute__((ext_vector_type(4))) float f32x4;

// d_out float offsets (loss, quantized, perplexity, embedding, indices, encodings)
#define O_Q    1
#define O_PERP 8388609
#define O_EMB  8388610
#define O_IDX  9437186
#define O_ENC  9469954

// workspace float offsets: ETpk limb image at byte 0 (4 MB)
#define W_CB   1048576
#define W_CNT  1052672
#define W_BS   1056768

#define MARGIN 0.4f

__device__ __forceinline__ unsigned short bf16_rne(float x) {
    unsigned u = __float_as_uint(x);
    unsigned r = u + 0x7FFFu + ((u >> 16) & 1u);
    return (unsigned short)(r >> 16);
}

__device__ __forceinline__ void gld_lds16(const void* g, void* l) {
    __builtin_amdgcn_global_load_lds(
        (const __attribute__((address_space(1))) unsigned int*)g,
        (__attribute__((address_space(3))) unsigned int*)l, 16, 0, 0);
}

__device__ __forceinline__ unsigned long long u64min(unsigned long long a, unsigned long long b){ return a < b ? a : b; }

__device__ __forceinline__ unsigned long long packkey(float s, int k) {
    unsigned u = __float_as_uint(s);
    u = (u & 0x80000000u) ? ~u : (u | 0x80000000u);
    return ((unsigned long long)u << 32) | (unsigned)k;
}
__device__ __forceinline__ float unpackf(unsigned long long key) {
    unsigned u = (unsigned)(key >> 32);
    u = (u & 0x80000000u) ? (u & 0x7FFFFFFFu) : ~u;
    return __uint_as_float(u);
}

// ---- E -> limb image. chunk(kt,ks) 32KB = [limb2][codefrag16][64 units x 16B]
// (k_main stages only the hi-limb 16KB half of each chunk)
__global__ __launch_bounds__(256)
void k_prepE(const float* __restrict__ E, char* __restrict__ ETpk)
{
    int gid = blockIdx.x * 256 + threadIdx.x;   // 131072 = 4096 codes * 32 octets
    int code = gid >> 5, oct = gid & 31;
    const float* ep = E + (size_t)code * 256 + oct * 8;
    float4 a = *(const float4*)ep, c4 = *(const float4*)(ep + 4);
    float v[8] = {a.x, a.y, a.z, a.w, c4.x, c4.y, c4.z, c4.w};
    unsigned hw[8], lw[8];
#pragma unroll
    for (int i = 0; i < 8; ++i) {
        unsigned short h = bf16_rne(v[i]);
        float hf = __uint_as_float((unsigned)h << 16);
        hw[i] = h; lw[i] = bf16_rne(v[i] - hf);
    }
    uint4 vh = {hw[0]|(hw[1]<<16), hw[2]|(hw[3]<<16), hw[4]|(hw[5]<<16), hw[6]|(hw[7]<<16)};
    uint4 vl = {lw[0]|(lw[1]<<16), lw[2]|(lw[3]<<16), lw[4]|(lw[5]<<16), lw[6]|(lw[7]<<16)};
    int kt = code >> 8, cf = (code >> 4) & 15, row = code & 15;
    int dtv = oct >> 2, c = oct & 3;
    size_t chunk = (size_t)(kt * 8 + dtv) * 32768;
    *(uint4*)(ETpk + chunk + (size_t)((0*16 + cf) * 64 + (c*16 + row)) * 16) = vh;
    *(uint4*)(ETpk + chunk + (size_t)((1*16 + cf) * 64 + (c*16 + row)) * 16) = vl;
}

// ---- 0.5*||e_k||^2 (fp32)
__global__ __launch_bounds__(256)
void k_cbias(const float* __restrict__ E, float* __restrict__ cb)
{
    const int tid = threadIdx.x;
    const int k   = blockIdx.x * 16 + (tid >> 4);
    const int ch  = tid & 15;
    const float* p = E + (size_t)k * 256 + ch * 16;
    float s = 0.f;
#pragma unroll
    for (int i = 0; i < 4; ++i) {
        float4 v = *(const float4*)(p + i * 4);
        s += v.x*v.x + v.y*v.y + v.z*v.z + v.w*v.w;
    }
#pragma unroll
    for (int m = 1; m < 16; m <<= 1) s += __shfl_xor(s, m, 64);
    if (ch == 0) cb[k] = 0.5f * s;
}

// ---- main: 2-combo (hh+lh) limb MFMA, per-lane top2 + pool rescore.
// grid 1024, block 512 (8 waves 2Mx4N), tile 32 tok x 256 codes/kt.
// LDS 80KB: A resident 32KB [ks8][limb2][frag2][1KB]; B-hi triple 3x16KB.
// => 2 blocks/CU, 16 waves/CU.
__global__ __launch_bounds__(512, 4)
void k_main(const float* __restrict__ X, const char* __restrict__ ETpk,
            const float* __restrict__ cbh, const float* __restrict__ E,
            float* __restrict__ out, int* __restrict__ counts,
            float* __restrict__ bscore)
{
    extern __shared__ char lds[];
    char* Alds = lds;                 // 32 KB
    char* Bsl  = lds + 32768;         // 3 x 16 KB

    const int tid  = threadIdx.x;
    const int lane = tid & 63;
    const int wid  = tid >> 6;
    const int wm   = wid >> 2;        // 0..1 token half (16 tok)
    const int wn   = wid & 3;         // 0..3 code quarter (64 codes)
    const int n0   = blockIdx.x * 32;
    const int b    = n0 >> 10;
    const int l0   = n0 & 1023;
    const size_t xbase = (size_t)b * 262144 + l0;
    float* encB = out + (size_t)O_ENC + (size_t)n0 * 4096;   // ≡ 2 mod 4: float2 ops

    f32x4 acc[4];
#pragma unroll
    for (int nj = 0; nj < 4; ++nj) acc[nj] = (f32x4){0.f,0.f,0.f,0.f};

    // per-lane top2 per slot q (4 token-rows); exact scan order not required
    float s1[4], s2v[4];
    unsigned ipack[4];
#pragma unroll
    for (int s = 0; s < 4; ++s) { s1[s] = FLT_MAX; s2v[s] = FLT_MAX; ipack[s] = 0; }

    auto stageB = [&](int rnd, int slot) {
        const char* src = ETpk + (size_t)rnd * 32768;   // hi-limb = first 16KB
        char* dst = Bsl + slot * 16384;
#pragma unroll
        for (int i = 0; i < 2; ++i)
            gld_lds16(src + i*8192 + tid*16, dst + i*8192 + tid*16);
    };

    // ---- prologue: stage B0,B1; load+split+write the 32-tok A tile once
    stageB(0, 0);
    stageB(1, 1);
#pragma unroll
    for (int pi = 0; pi < 2; ++pi) {
        const int p = pi * 512 + tid;         // 1024 = 32 tok x 32 d-octets
        const int t = p & 31, j = p >> 5;
        const int ks = j >> 2, c = j & 3;
        const float* xp = X + xbase + (size_t)(j * 8) * 1024 + t;
        float v[8];
#pragma unroll
        for (int i = 0; i < 8; ++i) v[i] = xp[(size_t)i * 1024];
        unsigned hw[8], lw[8];
#pragma unroll
        for (int i = 0; i < 8; ++i) {
            unsigned short h = bf16_rne(v[i]);
            float hf = __uint_as_float((unsigned)h << 16);
            hw[i] = h; lw[i] = bf16_rne(v[i] - hf);
        }
        uint4 vh = {hw[0]|(hw[1]<<16), hw[2]|(hw[3]<<16), hw[4]|(hw[5]<<16), hw[6]|(hw[7]<<16)};
        uint4 vl = {lw[0]|(lw[1]<<16), lw[2]|(lw[3]<<16), lw[4]|(lw[5]<<16), lw[6]|(lw[7]<<16)};
        char* d0 = Alds + ks * 4096 + (t >> 4) * 1024 + (c * 16 + (t & 15)) * 16;
        *(uint4*)d0          = vh;      // hi limb
        *(uint4*)(d0 + 2048) = vl;      // lo limb
    }
    __syncthreads();

    // ---- main loop: 16 kt x 8 ks = 128 k32-steps
#pragma unroll 1
    for (int kt = 0; kt < 16; ++kt) {
#pragma unroll 1
        for (int ks = 0; ks < 8; ++ks) {
            const int rd = kt * 8 + ks;
            const char* A  = Alds + ks * 4096 + wm * 1024;
            const char* Bp = Bsl + (rd % 3) * 16384;
            const int r2 = (rd + 2 < 128) ? rd + 2 : 127;
            stageB(r2, (rd + 2) % 3);
            {   // zero-fill 4KB of the one-hot region (1 float2/thread)
                const int lin = rd * 1024 + tid * 2;
                *(float2*)(encB + (size_t)(lin >> 12) * 4096 + (lin & 4095)) =
                    make_float2(0.f, 0.f);
            }
            bf16x8 ah = *(const bf16x8*)(A + lane * 16);
            bf16x8 al = *(const bf16x8*)(A + 2048 + lane * 16);
#pragma unroll
            for (int nj = 0; nj < 4; ++nj) {
                bf16x8 bh = *(const bf16x8*)(Bp + (wn*4 + nj)*1024 + lane*16);
                acc[nj] = __builtin_amdgcn_mfma_f32_16x16x32_bf16(ah, bh, acc[nj], 0, 0, 0);
                acc[nj] = __builtin_amdgcn_mfma_f32_16x16x32_bf16(al, bh, acc[nj], 0, 0, 0);
            }
            // counted wait: leave this iter's {2 stageB, 1 store} in flight;
            // everything older (incl. stageB(rd+1)) complete
            asm volatile("s_waitcnt vmcnt(3)" ::: "memory");
            __builtin_amdgcn_s_barrier();
        }
        // per-kt score + per-lane top2 (code = kt*256 + wn*64 + nj*16 + (lane&15))
        {
            const int cb0 = kt * 256 + wn * 64 + (lane & 15);
            float cbv[4];
#pragma unroll
            for (int nj = 0; nj < 4; ++nj) cbv[nj] = cbh[cb0 + nj * 16];
#pragma unroll
            for (int q = 0; q < 4; ++q)
#pragma unroll
                for (int nj = 0; nj < 4; ++nj) {
                    float s = cbv[nj] - acc[nj][q];
                    unsigned code = (unsigned)(cb0 + nj * 16);
                    if (s < s1[q]) {
                        s2v[q] = s1[q];
                        ipack[q] = ((ipack[q] & 0xFFFFu) << 16) | code;
                        s1[q] = s;
                    } else if (s < s2v[q]) {
                        s2v[q] = s;
                        ipack[q] = (ipack[q] & 0xFFFFu) | (code << 16);
                    }
                    acc[nj][q] = 0.f;
                }
        }
    }

    asm volatile("s_waitcnt vmcnt(0)" ::: "memory");
    __syncthreads();   // drain zero-fill stores (zero -> one-hot ordering) + LDS reuse

    // ---- dump per-lane top2 keys: scr[(t*64 + col)] = {key1, key2}
    ulonglong2* scr = (ulonglong2*)lds;          // 32 tok x 64 cols x 16B = 32 KB
    int*   ids = (int*)(lds + 32768);
    float* wp  = (float*)(lds + 32768 + 128);
    {
        const int col = wn * 16 + (lane & 15);
#pragma unroll
        for (int q = 0; q < 4; ++q) {
            const int t = wm * 16 + ((lane >> 4) << 2) + q;
            ulonglong2 kk;
            kk.x = packkey(s1[q],  (int)(ipack[q] & 0xFFFFu));
            kk.y = packkey(s2v[q], (int)(ipack[q] >> 16));
            scr[t * 64 + col] = kk;
        }
    }
    __syncthreads();

    // ---- per-token pool scan + conditional exact rescore
    if (tid < 32) {
        const ulonglong2* row = scr + tid * 64;
        unsigned long long m = 0xFFFFFFFFFFFFFFFFull;
#pragma unroll 1
        for (int i0 = 0; i0 < 64; ++i0) {       // staggered start: fewer bank conflicts
            int i = (2 * tid + i0) & 63;
            m = u64min(m, row[i].x);            // key2 >= key1 always
        }
        int k = (int)(m & 0xFFFFull);
        const float thr = unpackf(m) + MARGIN;
        int cnt = 0;
#pragma unroll 1
        for (int i0 = 0; i0 < 64; ++i0) {
            int i = (2 * tid + i0) & 63;
            ulonglong2 kk = row[i];
            cnt += (unpackf(kk.x) <= thr) + (unpackf(kk.y) <= thr);
        }
        if (cnt > 1) {
            float bd = FLT_MAX; int bi = 0x7FFFFFFF;
#pragma unroll 1
            for (int i0 = 0; i0 < 64; ++i0) {
                int i = (2 * tid + i0) & 63;
                ulonglong2 kk = row[i];
#pragma unroll
                for (int h = 0; h < 2; ++h) {
                    unsigned long long key = h ? kk.y : kk.x;
                    if (unpackf(key) <= thr) {
                        int c = (int)(key & 0xFFFFull);
                        float d = 0.f;
                        for (int dd = 0; dd < 256; dd += 2) {
                            float xv0 = X[xbase + (size_t)dd * 1024 + tid];
                            float xv1 = X[xbase + (size_t)(dd + 1) * 1024 + tid];
                            float e0 = E[(size_t)c * 256 + dd];
                            float e1 = E[(size_t)c * 256 + dd + 1];
                            float f0 = xv0 - e0, f1 = xv1 - e1;
                            d += f0 * f0 + f1 * f1;
                        }
                        if (d < bd || (d == bd && c < bi)) { bd = d; bi = c; }
                    }
                }
            }
            k = bi;
        }
        ids[tid] = k;
        out[(size_t)O_IDX + n0 + tid] = (float)k;
        atomicAdd(&counts[k], 1);
        out[(size_t)O_ENC + (size_t)(n0 + tid) * 4096 + k] = 1.0f;
    }
    __syncthreads();

    // ---- fused quantize (STE arithmetic) + exact fp32 loss partial
    float dl = 0.f;
#pragma unroll 4
    for (int r = 0; r < 16; ++r) {
        int lin = r * 512 + tid;
        int d = lin >> 5, t = lin & 31;
        float q  = E[(size_t)ids[t] * 256 + d];
        float xv = X[xbase + (size_t)d * 1024 + t];
        out[(size_t)O_Q + xbase + (size_t)d * 1024 + t] = xv + (q - xv);
        float df = q - xv;
        dl += df * df;
    }
#pragma unroll
    for (int m = 1; m < 64; m <<= 1) dl += __shfl_xor(dl, m, 64);
    if (lane == 0) wp[wid] = dl;
    __syncthreads();
    if (tid == 0) {
        float s = 0.f;
#pragma unroll
        for (int w = 0; w < 8; ++w) s += wp[w];
        bscore[blockIdx.x] = s;
    }
}

// ---- scalars: loss + perplexity (1024 block partials)
__global__ __launch_bounds__(256)
void k_final(const float* __restrict__ bscore, const int* __restrict__ counts,
             float* __restrict__ out)
{
    const int tid = threadIdx.x;
    float s = bscore[tid] + bscore[tid + 256] + bscore[tid + 512] + bscore[tid + 768];
    float h = 0.f;
#pragma unroll
    for (int i = 0; i < 16; ++i) {
        float p = (float)counts[tid * 16 + i] * (1.0f / 32768.f);
        h += p * logf(p + 1e-10f);
    }
#pragma unroll
    for (int m = 1; m < 64; m <<= 1) {
        s += __shfl_xor(s, m, 64);
        h += __shfl_xor(h, m, 64);
    }
    __shared__ float rs[4], rh[4];
    if ((tid & 63) == 0) { rs[tid >> 6] = s; rh[tid >> 6] = h; }
    __syncthreads();
    if (tid == 0) {
        float S = rs[0] + rs[1] + rs[2] + rs[3];
        float H = rh[0] + rh[1] + rh[2] + rh[3];
        out[0]      = 0.25f * S / 8388608.f;
        out[O_PERP] = expf(-H);
    }
}

extern "C" void kernel_launch(void* const* d_in, const int* in_sizes, int n_in,
                              void* d_out, int out_size, void* d_ws, size_t ws_size,
                              hipStream_t stream)
{
    (void)in_sizes; (void)n_in; (void)out_size; (void)ws_size;
    const float* X = (const float*)d_in[0];
    const float* E = (const float*)d_in[1];
    float* out = (float*)d_out;
    float* ws  = (float*)d_ws;
    char*  ETpk   = (char*)ws;
    float* cbh    = ws + W_CB;
    int*   counts = (int*)(ws + W_CNT);
    float* bsc    = ws + W_BS;

    hipMemsetAsync(counts, 0, 4096 * sizeof(int), stream);
    k_prepE<<<512, 256, 0, stream>>>(E, ETpk);
    k_cbias<<<256, 256, 0, stream>>>(E, cbh);
    hipFuncSetAttribute(reinterpret_cast<const void*>(&k_main),
                        hipFuncAttributeMaxDynamicSharedMemorySize, 81920);
    k_main <<<1024, 512, 81920, stream>>>(X, ETpk, cbh, E, out, counts, bsc);
    k_final<<<1, 256, 0, stream>>>(bsc, counts, out);
    hipMemcpyAsync(out + O_EMB, E, (size_t)4096 * 256 * sizeof(float),
                   hipMemcpyDeviceToDevice, stream);
}

// Round 10
// 370.280 us; speedup vs baseline: 1.2418x; 1.0227x over previous
//
#include <hip/hip_runtime.h>
#include <float.h>
#include <math.h>

typedef __attribute__((ext_vector_type(8))) short bf16x8;
typedef __attribute__((ext_vector_type(4))) float f32x4;

// d_out float offsets (loss, quantized, perplexity, embedding, indices, encodings)
#define O_Q    1
#define O_PERP 8388609
#define O_EMB  8388610
#define O_IDX  9437186
#define O_ENC  9469954

// workspace float offsets: ETpk hi-limb image at byte 0 (2 MB)
#define W_CB   1048576
#define W_CNT  1052672
#define W_BS   1056768

#define MARGIN 0.4f

__device__ __forceinline__ unsigned short bf16_rne(float x) {
    unsigned u = __float_as_uint(x);
    unsigned r = u + 0x7FFFu + ((u >> 16) & 1u);
    return (unsigned short)(r >> 16);
}

__device__ __forceinline__ void gld_lds16(const void* g, void* l) {
    __builtin_amdgcn_global_load_lds(
        (const __attribute__((address_space(1))) unsigned int*)g,
        (__attribute__((address_space(3))) unsigned int*)l, 16, 0, 0);
}

__device__ __forceinline__ unsigned long long u64min(unsigned long long a, unsigned long long b){ return a < b ? a : b; }

__device__ __forceinline__ unsigned long long packkey(float s, int k) {
    unsigned u = __float_as_uint(s);
    u = (u & 0x80000000u) ? ~u : (u | 0x80000000u);
    return ((unsigned long long)u << 32) | (unsigned)k;
}
__device__ __forceinline__ float unpackf(unsigned long long key) {
    unsigned u = (unsigned)(key >> 32);
    u = (u & 0x80000000u) ? (u & 0x7FFFFFFFu) : ~u;
    return __uint_as_float(u);
}

// ---- E -> hi-limb image. chunk(kt,ks) 16KB = [codefrag16][64 units x 16B]
__global__ __launch_bounds__(256)
void k_prepE(const float* __restrict__ E, char* __restrict__ ETpk)
{
    int gid = blockIdx.x * 256 + threadIdx.x;   // 131072 = 4096 codes * 32 octets
    int code = gid >> 5, oct = gid & 31;
    const float* ep = E + (size_t)code * 256 + oct * 8;
    float4 a = *(const float4*)ep, c4 = *(const float4*)(ep + 4);
    float v[8] = {a.x, a.y, a.z, a.w, c4.x, c4.y, c4.z, c4.w};
    unsigned hw[8];
#pragma unroll
    for (int i = 0; i < 8; ++i) hw[i] = bf16_rne(v[i]);
    uint4 vh = {hw[0]|(hw[1]<<16), hw[2]|(hw[3]<<16), hw[4]|(hw[5]<<16), hw[6]|(hw[7]<<16)};
    int kt = code >> 8, cf = (code >> 4) & 15, row = code & 15;
    int dtv = oct >> 2, c = oct & 3;
    size_t chunk = (size_t)(kt * 8 + dtv) * 16384;
    *(uint4*)(ETpk + chunk + (size_t)(cf * 64 + (c*16 + row)) * 16) = vh;
}

// ---- 0.5*||e_k||^2 (fp32)
__global__ __launch_bounds__(256)
void k_cbias(const float* __restrict__ E, float* __restrict__ cb)
{
    const int tid = threadIdx.x;
    const int k   = blockIdx.x * 16 + (tid >> 4);
    const int ch  = tid & 15;
    const float* p = E + (size_t)k * 256 + ch * 16;
    float s = 0.f;
#pragma unroll
    for (int i = 0; i < 4; ++i) {
        float4 v = *(const float4*)(p + i * 4);
        s += v.x*v.x + v.y*v.y + v.z*v.z + v.w*v.w;
    }
#pragma unroll
    for (int m = 1; m < 16; m <<= 1) s += __shfl_xor(s, m, 64);
    if (ch == 0) cb[k] = 0.5f * s;
}

// ---- main: A-in-registers 2-combo (hh+lh) limb MFMA, per-lane top2 + pool rescore.
// grid 1024, block 512 (8 waves 2Mx4N), tile 32 tok x 256 codes/kt.
// A frags: 64 VGPR/lane (8 ks x 2 limbs), loaded+split ONCE in prologue.
// LDS 48KB: B-hi triple-buffered 3x16KB staged 2 rds ahead. 2 blocks/CU.
// Per rd: 2 gld_lds + 1 zero-store + 4 ds_read_b128 + 8 MFMA + vmcnt(3) + barrier.
__global__ __launch_bounds__(512, 4)
void k_main(const float* __restrict__ X, const char* __restrict__ ETpk,
            const float* __restrict__ cbh, const float* __restrict__ E,
            float* __restrict__ out, int* __restrict__ counts,
            float* __restrict__ bscore)
{
    extern __shared__ char lds[];
    char* Bsl = lds;                  // 3 x 16 KB

    const int tid  = threadIdx.x;
    const int lane = tid & 63;
    const int wid  = tid >> 6;
    const int wm   = wid >> 2;        // 0..1 token half (16 tok)
    const int wn   = wid & 3;         // 0..3 code quarter (64 codes)
    const int n0   = blockIdx.x * 32;
    const int b    = n0 >> 10;
    const int l0   = n0 & 1023;
    const size_t xbase = (size_t)b * 262144 + l0;
    float* encB = out + (size_t)O_ENC + (size_t)n0 * 4096;   // ≡ 2 mod 4: float2 ops

    f32x4 acc[4];
#pragma unroll
    for (int nj = 0; nj < 4; ++nj) acc[nj] = (f32x4){0.f,0.f,0.f,0.f};

    float s1[4], s2v[4];
    unsigned ipack[4];
#pragma unroll
    for (int s = 0; s < 4; ++s) { s1[s] = FLT_MAX; s2v[s] = FLT_MAX; ipack[s] = 0; }

    auto stageB = [&](int rnd, int slot) {
        const char* src = ETpk + (size_t)rnd * 16384;
        char* dst = Bsl + slot * 16384;
#pragma unroll
        for (int i = 0; i < 2; ++i)
            gld_lds16(src + i*8192 + tid*16, dst + i*8192 + tid*16);
    };

    // ---- prologue: stage B0,B1; load+split A fragments into registers
    stageB(0, 0);
    stageB(1, 1);
    bf16x8 ahf[8], alf[8];
    {
        const int t_l = wm * 16 + (lane & 15);     // token row of this lane
        const int c_l = lane >> 4;                 // k-chunk 0..3
        const float* xp = X + xbase + t_l;
#pragma unroll
        for (int ks = 0; ks < 8; ++ks) {
            const int d0 = ks * 32 + c_l * 8;
            float v[8];
#pragma unroll
            for (int i = 0; i < 8; ++i) v[i] = xp[(size_t)(d0 + i) * 1024];
            unsigned hw[8], lw[8];
#pragma unroll
            for (int i = 0; i < 8; ++i) {
                unsigned short h = bf16_rne(v[i]);
                float hf = __uint_as_float((unsigned)h << 16);
                hw[i] = h; lw[i] = bf16_rne(v[i] - hf);
            }
            uint4 vh = {hw[0]|(hw[1]<<16), hw[2]|(hw[3]<<16), hw[4]|(hw[5]<<16), hw[6]|(hw[7]<<16)};
            uint4 vl = {lw[0]|(lw[1]<<16), lw[2]|(lw[3]<<16), lw[4]|(lw[5]<<16), lw[6]|(lw[7]<<16)};
            ahf[ks] = *(bf16x8*)&vh;
            alf[ks] = *(bf16x8*)&vl;
        }
    }
    __syncthreads();

    // ---- main loop: 16 kt x 8 ks (ks fully unrolled -> static A-frag indexing)
#pragma unroll 1
    for (int kt = 0; kt < 16; ++kt) {
#pragma unroll
        for (int ks = 0; ks < 8; ++ks) {
            const int rd = kt * 8 + ks;
            const char* Bp = Bsl + (rd % 3) * 16384;
            const int r2 = (rd + 2 < 128) ? rd + 2 : 127;
            stageB(r2, (rd + 2) % 3);
            {   // zero-fill 4KB of the one-hot region (1 float2/thread)
                const int lin = rd * 1024 + tid * 2;
                *(float2*)(encB + (size_t)(lin >> 12) * 4096 + (lin & 4095)) =
                    make_float2(0.f, 0.f);
            }
#pragma unroll
            for (int nj = 0; nj < 4; ++nj) {
                bf16x8 bh = *(const bf16x8*)(Bp + (wn*4 + nj)*1024 + lane*16);
                acc[nj] = __builtin_amdgcn_mfma_f32_16x16x32_bf16(ahf[ks], bh, acc[nj], 0, 0, 0);
                acc[nj] = __builtin_amdgcn_mfma_f32_16x16x32_bf16(alf[ks], bh, acc[nj], 0, 0, 0);
            }
            // counted wait: leave this rd's {2 stageB, 1 store} in flight;
            // everything older (incl. stageB(rd+1)) complete
            asm volatile("s_waitcnt vmcnt(3)" ::: "memory");
            __builtin_amdgcn_s_barrier();
        }
        // per-kt score + per-lane top2 (code = kt*256 + wn*64 + nj*16 + (lane&15))
        {
            const int cb0 = kt * 256 + wn * 64 + (lane & 15);
            float cbv[4];
#pragma unroll
            for (int nj = 0; nj < 4; ++nj) cbv[nj] = cbh[cb0 + nj * 16];
#pragma unroll
            for (int q = 0; q < 4; ++q)
#pragma unroll
                for (int nj = 0; nj < 4; ++nj) {
                    float s = cbv[nj] - acc[nj][q];
                    unsigned code = (unsigned)(cb0 + nj * 16);
                    if (s < s1[q]) {
                        s2v[q] = s1[q];
                        ipack[q] = ((ipack[q] & 0xFFFFu) << 16) | code;
                        s1[q] = s;
                    } else if (s < s2v[q]) {
                        s2v[q] = s;
                        ipack[q] = (ipack[q] & 0xFFFFu) | (code << 16);
                    }
                    acc[nj][q] = 0.f;
                }
        }
    }

    asm volatile("s_waitcnt vmcnt(0)" ::: "memory");
    __syncthreads();   // drain zero-fill stores (zero -> one-hot ordering) + LDS reuse

    // ---- dump per-lane top2 keys: scr[(t*64 + col)] = {key1, key2}
    ulonglong2* scr = (ulonglong2*)lds;          // 32 tok x 64 cols x 16B = 32 KB
    int*   ids = (int*)(lds + 32768);
    float* wp  = (float*)(lds + 32768 + 128);
    {
        const int col = wn * 16 + (lane & 15);
#pragma unroll
        for (int q = 0; q < 4; ++q) {
            const int t = wm * 16 + ((lane >> 4) << 2) + q;
            ulonglong2 kk;
            kk.x = packkey(s1[q],  (int)(ipack[q] & 0xFFFFu));
            kk.y = packkey(s2v[q], (int)(ipack[q] >> 16));
            scr[t * 64 + col] = kk;
        }
    }
    __syncthreads();

    // ---- per-token pool scan + conditional exact rescore
    if (tid < 32) {
        const ulonglong2* row = scr + tid * 64;
        unsigned long long m = 0xFFFFFFFFFFFFFFFFull;
#pragma unroll 1
        for (int i0 = 0; i0 < 64; ++i0) {       // staggered start: fewer bank conflicts
            int i = (2 * tid + i0) & 63;
            m = u64min(m, row[i].x);            // key2 >= key1 always
        }
        int k = (int)(m & 0xFFFFull);
        const float thr = unpackf(m) + MARGIN;
        int cnt = 0;
#pragma unroll 1
        for (int i0 = 0; i0 < 64; ++i0) {
            int i = (2 * tid + i0) & 63;
            ulonglong2 kk = row[i];
            cnt += (unpackf(kk.x) <= thr) + (unpackf(kk.y) <= thr);
        }
        if (cnt > 1) {
            float bd = FLT_MAX; int bi = 0x7FFFFFFF;
#pragma unroll 1
            for (int i0 = 0; i0 < 64; ++i0) {
                int i = (2 * tid + i0) & 63;
                ulonglong2 kk = row[i];
#pragma unroll
                for (int h = 0; h < 2; ++h) {
                    unsigned long long key = h ? kk.y : kk.x;
                    if (unpackf(key) <= thr) {
                        int c = (int)(key & 0xFFFFull);
                        float d = 0.f;
                        for (int dd = 0; dd < 256; dd += 2) {
                            float xv0 = X[xbase + (size_t)dd * 1024 + tid];
                            float xv1 = X[xbase + (size_t)(dd + 1) * 1024 + tid];
                            float e0 = E[(size_t)c * 256 + dd];
                            float e1 = E[(size_t)c * 256 + dd + 1];
                            float f0 = xv0 - e0, f1 = xv1 - e1;
                            d += f0 * f0 + f1 * f1;
                        }
                        if (d < bd || (d == bd && c < bi)) { bd = d; bi = c; }
                    }
                }
            }
            k = bi;
        }
        ids[tid] = k;
        out[(size_t)O_IDX + n0 + tid] = (float)k;
        atomicAdd(&counts[k], 1);
        out[(size_t)O_ENC + (size_t)(n0 + tid) * 4096 + k] = 1.0f;
    }
    __syncthreads();

    // ---- fused quantize (STE arithmetic) + exact fp32 loss partial
    float dl = 0.f;
#pragma unroll 4
    for (int r = 0; r < 16; ++r) {
        int lin = r * 512 + tid;
        int d = lin >> 5, t = lin & 31;
        float q  = E[(size_t)ids[t] * 256 + d];
        float xv = X[xbase + (size_t)d * 1024 + t];
        out[(size_t)O_Q + xbase + (size_t)d * 1024 + t] = xv + (q - xv);
        float df = q - xv;
        dl += df * df;
    }
#pragma unroll
    for (int m = 1; m < 64; m <<= 1) dl += __shfl_xor(dl, m, 64);
    if (lane == 0) wp[wid] = dl;
    __syncthreads();
    if (tid == 0) {
        float s = 0.f;
#pragma unroll
        for (int w = 0; w < 8; ++w) s += wp[w];
        bscore[blockIdx.x] = s;
    }
}

// ---- scalars: loss + perplexity (1024 block partials)
__global__ __launch_bounds__(256)
void k_final(const float* __restrict__ bscore, const int* __restrict__ counts,
             float* __restrict__ out)
{
    const int tid = threadIdx.x;
    float s = bscore[tid] + bscore[tid + 256] + bscore[tid + 512] + bscore[tid + 768];
    float h = 0.f;
#pragma unroll
    for (int i = 0; i < 16; ++i) {
        float p = (float)counts[tid * 16 + i] * (1.0f / 32768.f);
        h += p * logf(p + 1e-10f);
    }
#pragma unroll
    for (int m = 1; m < 64; m <<= 1) {
        s += __shfl_xor(s, m, 64);
        h += __shfl_xor(h, m, 64);
    }
    __shared__ float rs[4], rh[4];
    if ((tid & 63) == 0) { rs[tid >> 6] = s; rh[tid >> 6] = h; }
    __syncthreads();
    if (tid == 0) {
        float S = rs[0] + rs[1] + rs[2] + rs[3];
        float H = rh[0] + rh[1] + rh[2] + rh[3];
        out[0]      = 0.25f * S / 8388608.f;
        out[O_PERP] = expf(-H);
    }
}

extern "C" void kernel_launch(void* const* d_in, const int* in_sizes, int n_in,
                              void* d_out, int out_size, void* d_ws, size_t ws_size,
                              hipStream_t stream)
{
    (void)in_sizes; (void)n_in; (void)out_size; (void)ws_size;
    const float* X = (const float*)d_in[0];
    const float* E = (const float*)d_in[1];
    float* out = (float*)d_out;
    float* ws  = (float*)d_ws;
    char*  ETpk   = (char*)ws;
    float* cbh    = ws + W_CB;
    int*   counts = (int*)(ws + W_CNT);
    float* bsc    = ws + W_BS;

    hipMemsetAsync(counts, 0, 4096 * sizeof(int), stream);
    k_prepE<<<512, 256, 0, stream>>>(E, ETpk);
    k_cbias<<<256, 256, 0, stream>>>(E, cbh);
    hipFuncSetAttribute(reinterpret_cast<const void*>(&k_main),
                        hipFuncAttributeMaxDynamicSharedMemorySize, 49152);
    k_main <<<1024, 512, 49152, stream>>>(X, ETpk, cbh, E, out, counts, bsc);
    k_final<<<1, 256, 0, stream>>>(bsc, counts, out);
    hipMemcpyAsync(out + O_EMB, E, (size_t)4096 * 256 * sizeof(float),
                   hipMemcpyDeviceToDevice, stream);
}